// Round 5
// baseline (754.653 us; speedup 1.0000x reference)
//
#include <hip/hip_runtime.h>
#include <hip/hip_bf16.h>
#include <math.h>

#define S_LEN 256
#define B_SZ  512
#define D_DIM 1024
#define CAND_ 1024

// ---------------------------------------------------------------------------
// Kernel 1: x_ = x @ W^T (+ bias on split 0)  -> xwp[kz][b][d], f32
// Split-K GEMM: 32(b) x 64(d) tile, K-step 32, 256 threads, 2x4 per thread.
// grid (B/32, D/64, ksplit) -> 512 blocks at ksplit=2 (2 blocks/CU).
// ---------------------------------------------------------------------------
#define TB 32
#define TD 64
#define TK 32

__launch_bounds__(256, 2)
__global__ void transform_gemm(const float* __restrict__ x,
                               const float* __restrict__ W,
                               const float* __restrict__ bias,
                               float* __restrict__ xwp,
                               int ksplit) {
    __shared__ float xt[TK][TB + 2];   // [k][b]
    __shared__ float wt[TK][TD + 4];   // [k][d]

    const int b0 = blockIdx.x * TB;
    const int d0 = blockIdx.y * TD;
    const int kz = blockIdx.z;
    const int kspan = CAND_ / ksplit;
    const int kbase = kz * kspan;

    const int t  = threadIdx.x;
    const int td = t & 15;             // 0..15 -> 4 d's
    const int tb = t >> 4;             // 0..15 -> 2 b's

    float acc0[4] = {0.f, 0.f, 0.f, 0.f};
    float acc1[4] = {0.f, 0.f, 0.f, 0.f};

    const int xr  = t >> 3;            // 0..31
    const int xkc = t & 7;             // 0..7

    for (int k0 = kbase; k0 < kbase + kspan; k0 += TK) {
        {
            float4 xv = *(const float4*)&x[(size_t)(b0 + xr) * CAND_ + k0 + xkc * 4];
            xt[xkc * 4 + 0][xr] = xv.x;
            xt[xkc * 4 + 1][xr] = xv.y;
            xt[xkc * 4 + 2][xr] = xv.z;
            xt[xkc * 4 + 3][xr] = xv.w;
        }
        #pragma unroll
        for (int h = 0; h < 2; ++h) {
            int c   = t + h * 256;
            int wr  = c >> 3;          // 0..63
            int wkc = c & 7;           // 0..7
            float4 wv = *(const float4*)&W[(size_t)(d0 + wr) * CAND_ + k0 + wkc * 4];
            wt[wkc * 4 + 0][wr] = wv.x;
            wt[wkc * 4 + 1][wr] = wv.y;
            wt[wkc * 4 + 2][wr] = wv.z;
            wt[wkc * 4 + 3][wr] = wv.w;
        }
        __syncthreads();
        #pragma unroll
        for (int k = 0; k < TK; ++k) {
            float2 xa = *(const float2*)&xt[k][tb * 2];
            float4 wv = *(const float4*)&wt[k][td * 4];
            acc0[0] = fmaf(xa.x, wv.x, acc0[0]);
            acc0[1] = fmaf(xa.x, wv.y, acc0[1]);
            acc0[2] = fmaf(xa.x, wv.z, acc0[2]);
            acc0[3] = fmaf(xa.x, wv.w, acc0[3]);
            acc1[0] = fmaf(xa.y, wv.x, acc1[0]);
            acc1[1] = fmaf(xa.y, wv.y, acc1[1]);
            acc1[2] = fmaf(xa.y, wv.z, acc1[2]);
            acc1[3] = fmaf(xa.y, wv.w, acc1[3]);
        }
        __syncthreads();
    }

    float bx = 0.f, by = 0.f, bz = 0.f, bw = 0.f;
    if (kz == 0) {
        const float4 bv = *(const float4*)&bias[d0 + td * 4];
        bx = bv.x; by = bv.y; bz = bv.z; bw = bv.w;
    }
    const int b = b0 + tb * 2;
    const int d = d0 + td * 4;
    float* dst = xwp + (size_t)kz * B_SZ * D_DIM;
    float4 o0 = {acc0[0] + bx, acc0[1] + by, acc0[2] + bz, acc0[3] + bw};
    float4 o1 = {acc1[0] + bx, acc1[1] + by, acc1[2] + bz, acc1[3] + bw};
    *(float4*)&dst[(size_t)b * D_DIM + d]       = o0;
    *(float4*)&dst[(size_t)(b + 1) * D_DIM + d] = o1;
}

// ---------------------------------------------------------------------------
// Kernel 2: fused scores + tanh + masked-softmax + renorm + pooling.
// One block per batch (512 thr = 8 waves, 32 s-rows/wave). Rows processed in
// PAIRS: two independent dot chains, interleaved dual butterfly (halves the
// exposed ds_swizzle latency), explicit 2-row prefetch pipeline with named
// registers. Mask row staged in LDS. Single pass over M (512 MiB HBM).
// ---------------------------------------------------------------------------
#define NW 8
#define NS (S_LEN / NW)

#define LOAD_ROW(r0, r1, r2, r3, sidx)                                        \
    do {                                                                      \
        const float4* _p = (const float4*)(M + ((size_t)(sidx) * B_SZ + b) * D_DIM); \
        r0 = _p[lane]; r1 = _p[lane + 64]; r2 = _p[lane + 128]; r3 = _p[lane + 192]; \
    } while (0)

#define DOT4(res, r0, r1, r2, r3)                                             \
    do {                                                                      \
        float _p0 = r0.x * x0.x; _p0 = fmaf(r0.y, x0.y, _p0);                 \
        _p0 = fmaf(r0.z, x0.z, _p0); _p0 = fmaf(r0.w, x0.w, _p0);             \
        float _p1 = r1.x * x1.x; _p1 = fmaf(r1.y, x1.y, _p1);                 \
        _p1 = fmaf(r1.z, x1.z, _p1); _p1 = fmaf(r1.w, x1.w, _p1);             \
        float _p2 = r2.x * x2.x; _p2 = fmaf(r2.y, x2.y, _p2);                 \
        _p2 = fmaf(r2.z, x2.z, _p2); _p2 = fmaf(r2.w, x2.w, _p2);             \
        float _p3 = r3.x * x3.x; _p3 = fmaf(r3.y, x3.y, _p3);                 \
        _p3 = fmaf(r3.z, x3.z, _p3); _p3 = fmaf(r3.w, x3.w, _p3);             \
        res = (_p0 + _p1) + (_p2 + _p3);                                      \
    } while (0)

#define ACCW(wgt, r0, r1, r2, r3)                                             \
    do {                                                                      \
        a0.x = fmaf(wgt, r0.x, a0.x); a0.y = fmaf(wgt, r0.y, a0.y);           \
        a0.z = fmaf(wgt, r0.z, a0.z); a0.w = fmaf(wgt, r0.w, a0.w);           \
        a1.x = fmaf(wgt, r1.x, a1.x); a1.y = fmaf(wgt, r1.y, a1.y);           \
        a1.z = fmaf(wgt, r1.z, a1.z); a1.w = fmaf(wgt, r1.w, a1.w);           \
        a2.x = fmaf(wgt, r2.x, a2.x); a2.y = fmaf(wgt, r2.y, a2.y);           \
        a2.z = fmaf(wgt, r2.z, a2.z); a2.w = fmaf(wgt, r2.w, a2.w);           \
        a3.x = fmaf(wgt, r3.x, a3.x); a3.y = fmaf(wgt, r3.y, a3.y);           \
        a3.z = fmaf(wgt, r3.z, a3.z); a3.w = fmaf(wgt, r3.w, a3.w);           \
    } while (0)

__launch_bounds__(512, 4)
__global__ void fused_attn(const float* __restrict__ M,
                           const float* __restrict__ mask,
                           const float* __restrict__ xw0,
                           const float* __restrict__ xw1,
                           float* __restrict__ out) {
    __shared__ float s_acc[NW][D_DIM];   // 32 KB
    __shared__ float s_w[S_LEN];
    __shared__ float s_mask[S_LEN];
    __shared__ float s_den[NW];

    const int b    = blockIdx.x;
    const int tid  = threadIdx.x;
    const int lane = tid & 63;
    const int wv   = tid >> 6;

    if (tid < S_LEN) s_mask[tid] = mask[(size_t)b * S_LEN + tid];

    // x_[b] = xw0[b] (+ xw1[b] if split-K): lane holds d = 4*lane + 256*j
    const float4* xp0 = (const float4*)(xw0 + (size_t)b * D_DIM);
    float4 x0 = xp0[lane];
    float4 x1 = xp0[lane + 64];
    float4 x2 = xp0[lane + 128];
    float4 x3 = xp0[lane + 192];
    if (xw1) {
        const float4* xp1 = (const float4*)(xw1 + (size_t)b * D_DIM);
        float4 y0 = xp1[lane], y1 = xp1[lane + 64], y2 = xp1[lane + 128], y3 = xp1[lane + 192];
        x0.x += y0.x; x0.y += y0.y; x0.z += y0.z; x0.w += y0.w;
        x1.x += y1.x; x1.y += y1.y; x1.z += y1.z; x1.w += y1.w;
        x2.x += y2.x; x2.y += y2.y; x2.z += y2.z; x2.w += y2.w;
        x3.x += y3.x; x3.y += y3.y; x3.z += y3.z; x3.w += y3.w;
    }
    __syncthreads();

    float4 a0 = {0, 0, 0, 0}, a1 = {0, 0, 0, 0}, a2 = {0, 0, 0, 0}, a3 = {0, 0, 0, 0};
    float denom = 0.f;

    const int s_begin = wv * NS;
    float4 c00, c01, c02, c03, c10, c11, c12, c13;
    LOAD_ROW(c00, c01, c02, c03, s_begin + 0);
    LOAD_ROW(c10, c11, c12, c13, s_begin + 1);

    #pragma unroll 2
    for (int i = 0; i < NS; i += 2) {
        float4 n00, n01, n02, n03, n10, n11, n12, n13;
        const bool more = (i + 2 < NS);
        if (more) {
            LOAD_ROW(n00, n01, n02, n03, s_begin + i + 2);
            LOAD_ROW(n10, n11, n12, n13, s_begin + i + 3);
        }
        float p, q;
        DOT4(p, c00, c01, c02, c03);
        DOT4(q, c10, c11, c12, c13);
        // dual interleaved butterfly: two independent 6-step chains
        #pragma unroll
        for (int off = 32; off > 0; off >>= 1) {
            p += __shfl_xor(p, off, 64);
            q += __shfl_xor(q, off, 64);
        }
        const float mk0 = s_mask[s_begin + i];
        const float mk1 = s_mask[s_begin + i + 1];
        const float w0 = mk0 * expf(tanhf(p * mk0 * mk0));
        const float w1 = mk1 * expf(tanhf(q * mk1 * mk1));
        denom += w0 + w1;
        if (lane == 0) {
            s_w[s_begin + i]     = w0;
            s_w[s_begin + i + 1] = w1;
        }
        ACCW(w0, c00, c01, c02, c03);
        ACCW(w1, c10, c11, c12, c13);
        if (more) {
            c00 = n00; c01 = n01; c02 = n02; c03 = n03;
            c10 = n10; c11 = n11; c12 = n12; c13 = n13;
        }
    }

    float* sa = &s_acc[wv][0];
    ((float4*)sa)[lane]       = a0;
    ((float4*)sa)[lane + 64]  = a1;
    ((float4*)sa)[lane + 128] = a2;
    ((float4*)sa)[lane + 192] = a3;
    if (lane == 0) s_den[wv] = denom;
    __syncthreads();

    float dtot = 0.f;
    #pragma unroll
    for (int w8 = 0; w8 < NW; ++w8) dtot += s_den[w8];
    const float inv = 1.0f / dtot;

    #pragma unroll
    for (int j = 0; j < 2; ++j) {
        const int d = tid * 2 + j;
        float v = 0.f;
        #pragma unroll
        for (int w8 = 0; w8 < NW; ++w8) v += s_acc[w8][d];
        out[(size_t)b * D_DIM + d] = v * inv;
    }
    if (tid < S_LEN) {
        out[(size_t)B_SZ * D_DIM + (size_t)b * S_LEN + tid] = s_w[tid] * inv;
    }
}

extern "C" void kernel_launch(void* const* d_in, const int* in_sizes, int n_in,
                              void* d_out, int out_size, void* d_ws, size_t ws_size,
                              hipStream_t stream) {
    (void)in_sizes; (void)n_in; (void)out_size;
    const float* M    = (const float*)d_in[0];   // (S, B, D)
    const float* x    = (const float*)d_in[1];   // (B, CAND)
    const float* mask = (const float*)d_in[2];   // (B, S)
    const float* W    = (const float*)d_in[3];   // (D, CAND)
    const float* bias = (const float*)d_in[4];   // (D,)
    float* out = (float*)d_out;

    const size_t xw_bytes = (size_t)B_SZ * D_DIM * sizeof(float);  // 2 MiB
    if (ws_size >= 2 * xw_bytes) {
        float* xwp = (float*)d_ws;
        dim3 g(B_SZ / TB, D_DIM / TD, 2);
        transform_gemm<<<g, 256, 0, stream>>>(x, W, bias, xwp, 2);
        fused_attn<<<B_SZ, 512, 0, stream>>>(M, mask, xwp, xwp + (size_t)B_SZ * D_DIM, out);
    } else {
        // fallback: single-K into the attn_pool region of out (block b reads
        // x_[b] before writing pool[b] -> no hazard)
        dim3 g(B_SZ / TB, D_DIM / TD, 1);
        transform_gemm<<<g, 256, 0, stream>>>(x, W, bias, out, 1);
        fused_attn<<<B_SZ, 512, 0, stream>>>(M, mask, out, nullptr, out);
    }
}